// Round 3
// baseline (278.339 us; speedup 1.0000x reference)
//
#include <hip/hip_runtime.h>
#include <hip/hip_fp16.h>

// GCN 3-layer encoder, aggregate-first form (A_hat commutes with W):
//   per layer: agg = D^-1/2 (A+I) D^-1/2 X   (gather in dim 64, fp16 staged)
//              out = act(agg @ W + b) [* dis, packed fp16 for next gather]
// CSR build: two-level bucketed (bucket = 256 dst nodes) so every random
// scatter lands in a block-owned LDS-cursored window -> no global atomics.
// LESSON (r3/r4): never take addresses of register data; cap tiled-GEMM K
// unroll at 2 (full unroll -> 256 VGPR + scratch spill).
// LESSON (r5/r7/r8): gather is latency/fetch-bound; fp16 staging halves bytes.
// LESSON (r9, FAILED fusion): per-node register GEMM needs 64 W VGPRs; the
// compiler refuses (VGPR=60 measured -> W reloaded per node) and the extra
// 24 shfl/node doubles DS-pipe time. Keep split gather->gemm.
// LESSON (r10): 16-lanes-own-4-features gather (no reduction butterfly) is
// worth ~16us/layer over the 8-slot butterfly layout.
// r11 (this round):
//  - gather: dynamic-bound inner loop capped MLP at ~2 outstanding loads.
//    Now: unrolled full-16 chunks + always-16-slot masked tail (unconditional
//    clamped loads, integer cndmask masking; fp16 0x0000 == +0.0) -> 16 loads
//    in flight, summation order preserved.
//  - gemm64: was DS-pipe-bound (8 b128/k-step on the shared LDS pipe). X now
//    read direct from global (16 lanes same address -> TA dedups, exactly-once
//    traffic); LDS holds only W -> VALU-bound.
//  - pairs packed to 1 int (src | (dst&255)<<17); prescale fused into
//    bucket_fill (block owns its 256 nodes' dis).
// NOTE: per-XCD L2 reuse for the gather is capped at deg/8 XCDs = 1.25 --
// dim-sliced multi-pass blocking computes to IDENTICAL fill traffic; don't try.

#define NBMAX 512   // max buckets (n <= 131072; src must fit 17 bits for packing)
#define EPB   4096  // edges per binning block (nblkA must stay <= 256)

// ---------------- bucketed CSR build ----------------

// A: per-block bucket histogram -> hist[block][bucket]
__global__ __launch_bounds__(256) void bin_hist(const int* __restrict__ dst,
                                                int* __restrict__ hist, int E, int NB) {
  __shared__ int cnt[NBMAX];
  for (int i = threadIdx.x; i < NB; i += 256) cnt[i] = 0;
  __syncthreads();
  int base = blockIdx.x * EPB;
  for (int it = 0; it < EPB; it += 256) {
    int e = base + it + threadIdx.x;
    if (e < E) atomicAdd(&cnt[dst[e] >> 8], 1);
  }
  __syncthreads();
  for (int i = threadIdx.x; i < NB; i += 256) hist[(size_t)blockIdx.x * NB + i] = cnt[i];
}

// B1: per bucket, exclusive scan over blocks (in place); totals out.
// Requires nblk <= 256 (E=1e6, EPB=4096 -> 245).
__global__ __launch_bounds__(256) void bucket_prefix(int* __restrict__ hist,
                                                     int* __restrict__ bucket_tot,
                                                     int nblk, int NB) {
  __shared__ int tmp[256];
  int b = blockIdx.x;
  int t = threadIdx.x;
  int v = (t < nblk) ? hist[(size_t)t * NB + b] : 0;
  tmp[t] = v;
  __syncthreads();
  for (int off = 1; off < 256; off <<= 1) {
    int a = (t >= off) ? tmp[t - off] : 0;
    __syncthreads();
    tmp[t] += a;
    __syncthreads();
  }
  if (t < nblk) hist[(size_t)t * NB + b] = tmp[t] - v;  // exclusive over blocks
  if (t == 255) bucket_tot[b] = tmp[255];
}

// B2: exclusive scan of bucket totals -> bucket_off[0..NB], bucket_off[NB]=E.
__global__ __launch_bounds__(512) void bucket_scan(const int* __restrict__ bucket_tot,
                                                   int* __restrict__ bucket_off, int NB, int E) {
  __shared__ int tmp[NBMAX];
  int t = threadIdx.x;
  int v = (t < NB) ? bucket_tot[t] : 0;
  tmp[t] = v;
  __syncthreads();
  for (int off = 1; off < 512; off <<= 1) {
    int a = (t >= off) ? tmp[t - off] : 0;
    __syncthreads();
    tmp[t] += a;
    __syncthreads();
  }
  if (t < NB) bucket_off[t] = tmp[t] - v;
  if (t == 0) bucket_off[NB] = E;
}

// C: scatter packed (src | (dst&255)<<17) into bucket regions, LDS cursors.
__global__ __launch_bounds__(256) void bin_scatter(const int* __restrict__ src,
                                                   const int* __restrict__ dst,
                                                   const int* __restrict__ chunk_excl,
                                                   const int* __restrict__ bucket_off,
                                                   int* __restrict__ pairs, int E, int NB) {
  __shared__ int cur[NBMAX];
  for (int i = threadIdx.x; i < NB; i += 256)
    cur[i] = bucket_off[i] + chunk_excl[(size_t)blockIdx.x * NB + i];
  __syncthreads();
  int base = blockIdx.x * EPB;
  for (int it = 0; it < EPB; it += 256) {
    int e = base + it + threadIdx.x;
    if (e < E) {
      int d = dst[e];
      int pos = atomicAdd(&cur[d >> 8], 1);
      pairs[pos] = src[e] | ((d & 255) << 17);
    }
  }
}

__device__ __forceinline__ unsigned int packh(float a, float b) {
  unsigned int lo = (unsigned int)__half_as_ushort(__float2half_rn(a));
  unsigned int hi = (unsigned int)__half_as_ushort(__float2half_rn(b));
  return lo | (hi << 16);
}

__device__ __forceinline__ void unpack_add(float& x0, float& x1, unsigned int u) {
  x0 += __half2float(__ushort_as_half((unsigned short)(u & 0xffffu)));
  x1 += __half2float(__ushort_as_half((unsigned short)(u >> 16)));
}

// D: per bucket: node histogram -> row_ptr + dis; CSR fill with LDS cursors;
//    fused prescale of this bucket's 256 rows: xs = fp16(x * dis[row]).
__global__ __launch_bounds__(256) void bucket_fill(const int* __restrict__ pairs,
                                                   const int* __restrict__ bucket_off,
                                                   int* __restrict__ row_ptr,
                                                   int* __restrict__ csr_src,
                                                   float* __restrict__ dis,
                                                   const float* __restrict__ x,
                                                   unsigned short* __restrict__ xs,
                                                   int n, int NB) {
  __shared__ int cnt[256];
  __shared__ int tmp[256];
  __shared__ int cur[256];
  __shared__ float sdis[256];
  int b = blockIdx.x;
  int t = threadIdx.x;
  int node_base = b << 8;
  int ebeg = bucket_off[b];
  int eend = bucket_off[b + 1];
  cnt[t] = 0;
  __syncthreads();
  for (int e = ebeg + t; e < eend; e += 256) {
    atomicAdd(&cnt[(pairs[e] >> 17) & 255], 1);
  }
  __syncthreads();
  int v = cnt[t];
  tmp[t] = v;
  __syncthreads();
  for (int off = 1; off < 256; off <<= 1) {
    int a = (t >= off) ? tmp[t - off] : 0;
    __syncthreads();
    tmp[t] += a;
    __syncthreads();
  }
  int excl = tmp[t] - v;
  int node = node_base + t;
  float s = rsqrtf((float)v + 1.0f);  // +1 = self-loop
  sdis[t] = s;
  if (node < n) {
    row_ptr[node] = ebeg + excl;
    dis[node] = s;
  }
  cur[t] = ebeg + excl;
  if (b == NB - 1 && t == 0) row_ptr[n] = eend;
  __syncthreads();
  for (int e = ebeg + t; e < eend; e += 256) {
    int p = pairs[e];
    int pos = atomicAdd(&cur[(p >> 17) & 255], 1);
    csr_src[pos] = p & 0x1FFFF;
  }
  // fused prescale: rows [node_base, node_base+rows) -> fp16, scaled by dis
  int rows = n - node_base;
  if (rows > 256) rows = 256;
  for (int i = t; i < rows * 8; i += 256) {  // 8 x (8-feature) chunks per row
    int r = i >> 3;
    float sc = sdis[r];
    const float4* p = (const float4*)(x + ((size_t)(node_base + r) * 64) + (i & 7) * 8);
    float4 f0 = p[0];
    float4 f1 = p[1];
    uint4 u;
    u.x = packh(f0.x * sc, f0.y * sc);
    u.y = packh(f0.z * sc, f0.w * sc);
    u.z = packh(f1.x * sc, f1.y * sc);
    u.w = packh(f1.z * sc, f1.w * sc);
    *(uint4*)(xs + (size_t)(node_base + r) * 64 + (i & 7) * 8) = u;
  }
}

// ------- gather (dim 64, fp16 in): agg[d] = dis[d]*(in[d] + sum in[s]) -------
// 16 lanes per node (4 nodes/wave), lane owns features [4*l15, 4*l15+4).
// r11: full-16 chunks fully unrolled; masked 16-slot tail with unconditional
// clamped loads (invalid lanes re-read the last edge's line; masked to +0.0
// via integer cndmask). 16 independent loads in flight per group.

__global__ __launch_bounds__(256) void gather64q(const int* __restrict__ row_ptr,
                                                 const int* __restrict__ csr_src,
                                                 const unsigned short* __restrict__ in,
                                                 const float* __restrict__ dis,
                                                 float* __restrict__ agg, int n) {
  int node = blockIdx.x * 16 + (threadIdx.x >> 4);
  int l15 = threadIdx.x & 15;       // feature slice [4*l15, 4*l15+4)
  int gbase = threadIdx.x & 48;     // group base lane within the wave
  if (node >= n) return;            // group-uniform

  int beg = row_ptr[node];
  int end = row_ptr[node + 1];

  float a0 = 0.f, a1 = 0.f, a2 = 0.f, a3 = 0.f;

  {  // self-loop
    uint2 q = *(const uint2*)(in + (size_t)node * 64 + l15 * 4);
    unpack_add(a0, a1, q.x); unpack_add(a2, a3, q.y);
  }

  int k = beg;
  // full chunks (deg >= 16: ~2.6% of nodes) -- no masking, fully unrolled
  for (; k + 16 <= end; k += 16) {
    int idx = csr_src[k + l15];
#pragma unroll
    for (int rr = 0; rr < 16; rr += 2) {
      int s0 = __shfl(idx, gbase + rr);
      int s1 = __shfl(idx, gbase + rr + 1);
      uint2 q0 = *(const uint2*)(in + (size_t)s0 * 64 + l15 * 4);
      uint2 q1 = *(const uint2*)(in + (size_t)s1 * 64 + l15 * 4);
      unpack_add(a0, a1, q0.x); unpack_add(a2, a3, q0.y);
      unpack_add(a0, a1, q1.x); unpack_add(a2, a3, q1.y);
    }
  }
  // masked tail: 16 slots, unconditional clamped loads, masked accumulate
  int cnt = end - k;                 // 0..15
  if (cnt > 0) {                     // group-uniform branch
    int ii = k + l15;
    int last = end - 1;              // cnt>0 -> last >= beg, safe
    ii = (ii < end) ? ii : last;
    int idx = csr_src[ii];
#pragma unroll
    for (int rr = 0; rr < 16; rr += 2) {
      int s0 = __shfl(idx, gbase + rr);
      int s1 = __shfl(idx, gbase + rr + 1);
      uint2 q0 = *(const uint2*)(in + (size_t)s0 * 64 + l15 * 4);
      uint2 q1 = *(const uint2*)(in + (size_t)s1 * 64 + l15 * 4);
      q0.x = (rr < cnt) ? q0.x : 0u;      // fp16 0x0000 == +0.0
      q0.y = (rr < cnt) ? q0.y : 0u;
      q1.x = (rr + 1 < cnt) ? q1.x : 0u;
      q1.y = (rr + 1 < cnt) ? q1.y : 0u;
      unpack_add(a0, a1, q0.x); unpack_add(a2, a3, q0.y);
      unpack_add(a0, a1, q1.x); unpack_add(a2, a3, q1.y);
    }
  }

  float sc = dis[node];
  *(float4*)&agg[(size_t)node * 64 + l15 * 4] =
      make_float4(a0 * sc, a1 * sc, a2 * sc, a3 * sc);
}

// ---------------- tiled GEMM (64-row x 64-col slab) ----------------
// out[r, cb+c] = act( sum_k X[r,k] W[k, cb+c] + b[cb+c] ) [* dis[r]]
// r11: X read direct from global -- 16 lanes of a row-group share one address
// (TA dedups), so X-tile traffic is exactly-once. LDS holds only W (4 b128
// per k-step on the DS pipe vs 128 FMA on VALU -> VALU-bound).

__device__ __forceinline__ void fma4(float4& a, float s, const float4 w) {
  a.x = fmaf(s, w.x, a.x);
  a.y = fmaf(s, w.y, a.y);
  a.z = fmaf(s, w.z, a.z);
  a.w = fmaf(s, w.w, a.w);
}

template <bool RELU, bool SCALE, bool OUTH>
__global__ __launch_bounds__(256, 4) void gemm64(const float* __restrict__ X,
                                                 const float* __restrict__ W,
                                                 const float* __restrict__ B,
                                                 const float* __restrict__ dis,
                                                 float* __restrict__ yF,
                                                 unsigned short* __restrict__ yH,
                                                 int n, int ldw) {
  __shared__ float Ws[64 * 64];
  int tid = threadIdx.x;
  int rb = blockIdx.x * 64;
  int cb = blockIdx.y * 64;

  for (int i = tid; i < 1024; i += 256) {
    int k = i >> 4, cq = (i & 15) << 2;
    *(float4*)&Ws[k * 64 + cq] = *(const float4*)&W[(size_t)k * ldw + cb + cq];
  }
  __syncthreads();

  int r0 = (tid >> 4) << 2;
  int c0 = (tid & 15) << 2;
  int gr0 = rb + r0;

  // clamped row pointers (tail block: values unused, stores guarded)
  const float* xp0 = X + (size_t)min(gr0 + 0, n - 1) * 64;
  const float* xp1 = X + (size_t)min(gr0 + 1, n - 1) * 64;
  const float* xp2 = X + (size_t)min(gr0 + 2, n - 1) * 64;
  const float* xp3 = X + (size_t)min(gr0 + 3, n - 1) * 64;

  float4 a0 = make_float4(0.f, 0.f, 0.f, 0.f);
  float4 a1 = a0, a2 = a0, a3 = a0;

#pragma unroll 2
  for (int kc = 0; kc < 64; kc += 4) {
    float4 x0 = *(const float4*)(xp0 + kc);
    float4 x1 = *(const float4*)(xp1 + kc);
    float4 x2 = *(const float4*)(xp2 + kc);
    float4 x3 = *(const float4*)(xp3 + kc);
    float4 w0 = *(const float4*)&Ws[(kc + 0) * 64 + c0];
    float4 w1 = *(const float4*)&Ws[(kc + 1) * 64 + c0];
    float4 w2 = *(const float4*)&Ws[(kc + 2) * 64 + c0];
    float4 w3 = *(const float4*)&Ws[(kc + 3) * 64 + c0];
    fma4(a0, x0.x, w0); fma4(a0, x0.y, w1); fma4(a0, x0.z, w2); fma4(a0, x0.w, w3);
    fma4(a1, x1.x, w0); fma4(a1, x1.y, w1); fma4(a1, x1.z, w2); fma4(a1, x1.w, w3);
    fma4(a2, x2.x, w0); fma4(a2, x2.y, w1); fma4(a2, x2.z, w2); fma4(a2, x2.w, w3);
    fma4(a3, x3.x, w0); fma4(a3, x3.y, w1); fma4(a3, x3.z, w2); fma4(a3, x3.w, w3);
  }

  float4 bb = *(const float4*)&B[cb + c0];
#pragma unroll
  for (int ri = 0; ri < 4; ++ri) {
    int gr = gr0 + ri;
    if (gr >= n) break;
    float4 v = (ri == 0) ? a0 : (ri == 1) ? a1 : (ri == 2) ? a2 : a3;
    v.x += bb.x; v.y += bb.y; v.z += bb.z; v.w += bb.w;
    if (RELU) {
      v.x = fmaxf(v.x, 0.f); v.y = fmaxf(v.y, 0.f);
      v.z = fmaxf(v.z, 0.f); v.w = fmaxf(v.w, 0.f);
    }
    if (SCALE) {
      float s = dis[gr];
      v.x *= s; v.y *= s; v.z *= s; v.w *= s;
    }
    if (OUTH) {
      uint2 u;
      u.x = packh(v.x, v.y);
      u.y = packh(v.z, v.w);
      *(uint2*)(yH + (size_t)gr * ldw + cb + c0) = u;
    } else {
      *(float4*)&yF[(size_t)gr * ldw + cb + c0] = v;
    }
  }
}

// ---------------- launch ----------------

extern "C" void kernel_launch(void* const* d_in, const int* in_sizes, int n_in,
                              void* d_out, int out_size, void* d_ws, size_t ws_size,
                              hipStream_t stream) {
  const float* x  = (const float*)d_in[0];
  const float* W1 = (const float*)d_in[1];
  const float* b1 = (const float*)d_in[2];
  const float* W2 = (const float*)d_in[3];
  const float* b2 = (const float*)d_in[4];
  const float* W3 = (const float*)d_in[5];
  const float* b3 = (const float*)d_in[6];
  const int*   ei = (const int*)d_in[7];

  const int n = in_sizes[0] / 64;   // 100000
  const int E = in_sizes[7] / 2;    // 1000000
  const int* src = ei;
  const int* dst = ei + E;

  const int NB    = (n + 255) >> 8;         // buckets (256 nodes each): 391
  const int nblkA = (E + EPB - 1) / EPB;    // binning blocks: 245

  // Workspace: dis[n] f32 | bufIn[n*64] fp16 | agg[n*64] f32 | row_ptr[n+2] |
  //            csr_src[E] | pairs[E] int | hist[nblkA*NB] | tot[NB] | off[NB+1]
  float* dis = (float*)d_ws;
  unsigned short* bufIn = (unsigned short*)(dis + n);
  float* agg = (float*)(bufIn + (size_t)n * 64);
  int* row_ptr = (int*)(agg + (size_t)n * 64);
  int* csr_src = row_ptr + (n + 2);
  int* pairs   = csr_src + E;
  int* hist       = pairs + E;
  int* bucket_tot = hist + (size_t)nblkA * NB;
  int* bucket_off = bucket_tot + NB;
  float* out = (float*)d_out;

  dim3 blk(256);
  int gW = (n + 15) / 16;         // gather: 16 nodes (4 waves x 4 groups) / block
  int gT = (n + 63) / 64;         // gemm: 64-row tiles

  // --- bucketed CSR build (+ dis, + fused prescale) ---
  bin_hist<<<nblkA, blk, 0, stream>>>(dst, hist, E, NB);
  bucket_prefix<<<NB, blk, 0, stream>>>(hist, bucket_tot, nblkA, NB);
  bucket_scan<<<1, 512, 0, stream>>>(bucket_tot, bucket_off, NB, E);
  bin_scatter<<<nblkA, blk, 0, stream>>>(src, dst, hist, bucket_off, pairs, E, NB);
  bucket_fill<<<NB, blk, 0, stream>>>(pairs, bucket_off, row_ptr, csr_src, dis, x, bufIn, n, NB);

  // --- Layer 1: gather -> gemm(relu, scale, fp16 out) ---
  gather64q<<<gW, blk, 0, stream>>>(row_ptr, csr_src, bufIn, dis, agg, n);
  gemm64<true, true, true><<<dim3(gT, 1), blk, 0, stream>>>(agg, W1, b1, dis, nullptr, bufIn, n, 64);

  // --- Layer 2 ---
  gather64q<<<gW, blk, 0, stream>>>(row_ptr, csr_src, bufIn, dis, agg, n);
  gemm64<true, true, true><<<dim3(gT, 1), blk, 0, stream>>>(agg, W2, b2, dis, nullptr, bufIn, n, 64);

  // --- Layer 3: gather -> gemm(fp32 out, 128 cols) ---
  gather64q<<<gW, blk, 0, stream>>>(row_ptr, csr_src, bufIn, dis, agg, n);
  gemm64<false, false, false><<<dim3(gT, 2), blk, 0, stream>>>(agg, W3, b3, dis, out, nullptr, n, 128);
}

// Round 4
// 253.384 us; speedup vs baseline: 1.0985x; 1.0985x over previous
//
#include <hip/hip_runtime.h>
#include <hip/hip_fp16.h>

// GCN 3-layer encoder, aggregate-first form (A_hat commutes with W):
//   per layer: Xs = D^-1/2 (A+I) D^-1/2 X  (gather, fp16 in, fp32 LDS tile)
//              out = act(Xs @ W + b) [* dis, packed fp16 for next layer]
// r12: gather and GEMM FUSED per layer at BLOCK level (not wave level -- r9's
// wave-level fusion failed on W register pressure + shuffle doubling).
// One block = 64 nodes: phase A gathers 4x16 nodes into LDS Xs (16-lane
// groups, lane owns 4 features, no reduction butterfly), phase B is the
// 64x64(xNCB) tiled GEMM reading Xs from LDS (16-way same-address broadcast
// -> cheap DS). Kills the 51 MB/layer agg global round-trip + 2 kernel
// boundaries per layer; W load overlaps gather latency; phases of different
// blocks overlap on a CU. Activations double-buffered (bufA<->bufB).
// CSR build: two-level bucketed (bucket = 256 dst nodes) so every random
// scatter lands in a block-owned LDS-cursored window -> no global atomics.
// LESSON (r3/r4): never take addresses of register data; cap GEMM K unroll
// at 2 (full unroll -> 256 VGPR + scratch spill).
// LESSON (r5/r7/r8): gather is latency/fetch-bound; fp16 staging halves bytes.
// LESSON (r9, FAILED): no wave-level matvec fusion (W wants 64 VGPR, compiler
// refuses; +24 shfl/node doubles DS time).
// LESSON (r10): 16-lanes-own-4-features gather beats butterfly by ~16us/layer.
// LESSON (r11, NEUTRAL): gather is NOT issue-limited -- 16-slot masked tail's
// wasted loads are same-line L1 hits; deep unroll bought nothing. Remaining
// cost is random-line service + interfaces -> hence r12's fusion.
// NOTE: per-XCD L2 reuse for the gather is capped at deg/8 XCDs = 1.25 --
// dim-sliced multi-pass blocking computes to IDENTICAL fill traffic; don't try.

#define NBMAX 512   // max buckets (n <= 131072; src must fit 17 bits for packing)
#define EPB   4096  // edges per binning block (nblkA must stay <= 256)

// ---------------- bucketed CSR build ----------------

// A: per-block bucket histogram -> hist[block][bucket]
__global__ __launch_bounds__(256) void bin_hist(const int* __restrict__ dst,
                                                int* __restrict__ hist, int E, int NB) {
  __shared__ int cnt[NBMAX];
  for (int i = threadIdx.x; i < NB; i += 256) cnt[i] = 0;
  __syncthreads();
  int base = blockIdx.x * EPB;
  for (int it = 0; it < EPB; it += 256) {
    int e = base + it + threadIdx.x;
    if (e < E) atomicAdd(&cnt[dst[e] >> 8], 1);
  }
  __syncthreads();
  for (int i = threadIdx.x; i < NB; i += 256) hist[(size_t)blockIdx.x * NB + i] = cnt[i];
}

// B1: per bucket, exclusive scan over blocks (in place); totals out.
// Requires nblk <= 256 (E=1e6, EPB=4096 -> 245).
__global__ __launch_bounds__(256) void bucket_prefix(int* __restrict__ hist,
                                                     int* __restrict__ bucket_tot,
                                                     int nblk, int NB) {
  __shared__ int tmp[256];
  int b = blockIdx.x;
  int t = threadIdx.x;
  int v = (t < nblk) ? hist[(size_t)t * NB + b] : 0;
  tmp[t] = v;
  __syncthreads();
  for (int off = 1; off < 256; off <<= 1) {
    int a = (t >= off) ? tmp[t - off] : 0;
    __syncthreads();
    tmp[t] += a;
    __syncthreads();
  }
  if (t < nblk) hist[(size_t)t * NB + b] = tmp[t] - v;  // exclusive over blocks
  if (t == 255) bucket_tot[b] = tmp[255];
}

// B2: exclusive scan of bucket totals -> bucket_off[0..NB], bucket_off[NB]=E.
__global__ __launch_bounds__(512) void bucket_scan(const int* __restrict__ bucket_tot,
                                                   int* __restrict__ bucket_off, int NB, int E) {
  __shared__ int tmp[NBMAX];
  int t = threadIdx.x;
  int v = (t < NB) ? bucket_tot[t] : 0;
  tmp[t] = v;
  __syncthreads();
  for (int off = 1; off < 512; off <<= 1) {
    int a = (t >= off) ? tmp[t - off] : 0;
    __syncthreads();
    tmp[t] += a;
    __syncthreads();
  }
  if (t < NB) bucket_off[t] = tmp[t] - v;
  if (t == 0) bucket_off[NB] = E;
}

// C: scatter packed (src | (dst&255)<<17) into bucket regions, LDS cursors.
__global__ __launch_bounds__(256) void bin_scatter(const int* __restrict__ src,
                                                   const int* __restrict__ dst,
                                                   const int* __restrict__ chunk_excl,
                                                   const int* __restrict__ bucket_off,
                                                   int* __restrict__ pairs, int E, int NB) {
  __shared__ int cur[NBMAX];
  for (int i = threadIdx.x; i < NB; i += 256)
    cur[i] = bucket_off[i] + chunk_excl[(size_t)blockIdx.x * NB + i];
  __syncthreads();
  int base = blockIdx.x * EPB;
  for (int it = 0; it < EPB; it += 256) {
    int e = base + it + threadIdx.x;
    if (e < E) {
      int d = dst[e];
      int pos = atomicAdd(&cur[d >> 8], 1);
      pairs[pos] = src[e] | ((d & 255) << 17);
    }
  }
}

__device__ __forceinline__ unsigned int packh(float a, float b) {
  unsigned int lo = (unsigned int)__half_as_ushort(__float2half_rn(a));
  unsigned int hi = (unsigned int)__half_as_ushort(__float2half_rn(b));
  return lo | (hi << 16);
}

__device__ __forceinline__ void unpack_add(float& x0, float& x1, unsigned int u) {
  x0 += __half2float(__ushort_as_half((unsigned short)(u & 0xffffu)));
  x1 += __half2float(__ushort_as_half((unsigned short)(u >> 16)));
}

// D: per bucket: node histogram -> row_ptr + dis; CSR fill with LDS cursors;
//    fused prescale of this bucket's 256 rows: xs = fp16(x * dis[row]).
__global__ __launch_bounds__(256) void bucket_fill(const int* __restrict__ pairs,
                                                   const int* __restrict__ bucket_off,
                                                   int* __restrict__ row_ptr,
                                                   int* __restrict__ csr_src,
                                                   float* __restrict__ dis,
                                                   const float* __restrict__ x,
                                                   unsigned short* __restrict__ xs,
                                                   int n, int NB) {
  __shared__ int cnt[256];
  __shared__ int tmp[256];
  __shared__ int cur[256];
  __shared__ float sdis[256];
  int b = blockIdx.x;
  int t = threadIdx.x;
  int node_base = b << 8;
  int ebeg = bucket_off[b];
  int eend = bucket_off[b + 1];
  cnt[t] = 0;
  __syncthreads();
  for (int e = ebeg + t; e < eend; e += 256) {
    atomicAdd(&cnt[(pairs[e] >> 17) & 255], 1);
  }
  __syncthreads();
  int v = cnt[t];
  tmp[t] = v;
  __syncthreads();
  for (int off = 1; off < 256; off <<= 1) {
    int a = (t >= off) ? tmp[t - off] : 0;
    __syncthreads();
    tmp[t] += a;
    __syncthreads();
  }
  int excl = tmp[t] - v;
  int node = node_base + t;
  float s = rsqrtf((float)v + 1.0f);  // +1 = self-loop
  sdis[t] = s;
  if (node < n) {
    row_ptr[node] = ebeg + excl;
    dis[node] = s;
  }
  cur[t] = ebeg + excl;
  if (b == NB - 1 && t == 0) row_ptr[n] = eend;
  __syncthreads();
  for (int e = ebeg + t; e < eend; e += 256) {
    int p = pairs[e];
    int pos = atomicAdd(&cur[(p >> 17) & 255], 1);
    csr_src[pos] = p & 0x1FFFF;
  }
  // fused prescale: rows [node_base, node_base+rows) -> fp16, scaled by dis
  int rows = n - node_base;
  if (rows > 256) rows = 256;
  for (int i = t; i < rows * 8; i += 256) {  // 8 x (8-feature) chunks per row
    int r = i >> 3;
    float sc = sdis[r];
    const float4* p = (const float4*)(x + ((size_t)(node_base + r) * 64) + (i & 7) * 8);
    float4 f0 = p[0];
    float4 f1 = p[1];
    uint4 u;
    u.x = packh(f0.x * sc, f0.y * sc);
    u.y = packh(f0.z * sc, f0.w * sc);
    u.z = packh(f1.x * sc, f1.y * sc);
    u.w = packh(f1.z * sc, f1.w * sc);
    *(uint4*)(xs + (size_t)(node_base + r) * 64 + (i & 7) * 8) = u;
  }
}

// ---------------- fused layer: gather(64 nodes) -> GEMM 64x(64*NCB) ----------
// Phase A: 16-lane groups gather node rows (fp16 in, fp32 acc) into LDS Xs.
//   Full-16 chunks unrolled; masked 16-slot tail (clamped loads hit the last
//   edge's line -> L1; fp16 0x0000 == +0.0 keeps summation order exact).
// Phase B: 64x64 tile GEMM per column-block cb: thread owns 4 rows x 4 cols.
//   Xs reads are 16-way same-address broadcasts (row-group shares address).
// out = act(Xs @ W + b) [* dis]; fp16-packed (OUTH) or fp32.

template <bool RELU, bool SCALE, bool OUTH, int NCB>
__global__ __launch_bounds__(256, 4) void gcn_layer(
    const int* __restrict__ row_ptr, const int* __restrict__ csr_src,
    const unsigned short* __restrict__ in, const float* __restrict__ dis,
    const float* __restrict__ W, const float* __restrict__ Bv,
    float* __restrict__ yF, unsigned short* __restrict__ yH, int n) {
  __shared__ float Xs[64 * 68];
  __shared__ float Ws[64 * 64 * NCB];
  int tid = threadIdx.x;
  int rb = blockIdx.x * 64;

  // W -> LDS first: global loads issue before gather, hide under its latency
  for (int i = tid; i < 64 * 16 * NCB; i += 256) {
    int k = i / (16 * NCB);
    int cq = (i % (16 * NCB)) << 2;
    *(float4*)&Ws[k * (64 * NCB) + cq] = *(const float4*)&W[(size_t)k * (64 * NCB) + cq];
  }

  // ---- Phase A: gather 64 rows (4 iters x 16 groups of 16 lanes) ----
  int l15 = tid & 15;    // feature slice [4*l15, 4*l15+4)
  int gbase = tid & 48;  // group base lane within the wave
  int grp = tid >> 4;    // group id 0..15
  for (int it = 0; it < 4; ++it) {
    int r = it * 16 + grp;           // local row 0..63
    int cl = min(rb + r, n - 1);     // clamped node (dup rows unused; stores guarded)
    int beg = row_ptr[cl];
    int end = row_ptr[cl + 1];

    float a0 = 0.f, a1 = 0.f, a2 = 0.f, a3 = 0.f;
    {  // self-loop
      uint2 q = *(const uint2*)(in + (size_t)cl * 64 + l15 * 4);
      unpack_add(a0, a1, q.x); unpack_add(a2, a3, q.y);
    }
    int k = beg;
    for (; k + 16 <= end; k += 16) {   // full chunks
      int idx = csr_src[k + l15];
#pragma unroll
      for (int rr = 0; rr < 16; rr += 2) {
        int s0 = __shfl(idx, gbase + rr);
        int s1 = __shfl(idx, gbase + rr + 1);
        uint2 q0 = *(const uint2*)(in + (size_t)s0 * 64 + l15 * 4);
        uint2 q1 = *(const uint2*)(in + (size_t)s1 * 64 + l15 * 4);
        unpack_add(a0, a1, q0.x); unpack_add(a2, a3, q0.y);
        unpack_add(a0, a1, q1.x); unpack_add(a2, a3, q1.y);
      }
    }
    int cnt = end - k;                 // 0..15, group-uniform
    if (cnt > 0) {                     // masked 16-slot tail
      int ii = k + l15;
      int last = end - 1;
      ii = (ii < end) ? ii : last;
      int idx = csr_src[ii];
#pragma unroll
      for (int rr = 0; rr < 16; rr += 2) {
        int s0 = __shfl(idx, gbase + rr);
        int s1 = __shfl(idx, gbase + rr + 1);
        uint2 q0 = *(const uint2*)(in + (size_t)s0 * 64 + l15 * 4);
        uint2 q1 = *(const uint2*)(in + (size_t)s1 * 64 + l15 * 4);
        q0.x = (rr < cnt) ? q0.x : 0u;      // fp16 0x0000 == +0.0
        q0.y = (rr < cnt) ? q0.y : 0u;
        q1.x = (rr + 1 < cnt) ? q1.x : 0u;
        q1.y = (rr + 1 < cnt) ? q1.y : 0u;
        unpack_add(a0, a1, q0.x); unpack_add(a2, a3, q0.y);
        unpack_add(a0, a1, q1.x); unpack_add(a2, a3, q1.y);
      }
    }
    float sc = dis[cl];
    *(float4*)&Xs[r * 68 + l15 * 4] =
        make_float4(a0 * sc, a1 * sc, a2 * sc, a3 * sc);
  }
  __syncthreads();

  // ---- Phase B: tiled GEMM from LDS ----
  int r0 = (tid >> 4) << 2;
  int c0 = (tid & 15) << 2;
  int gr0 = rb + r0;

#pragma unroll
  for (int cb = 0; cb < NCB; ++cb) {
    float4 a0 = make_float4(0.f, 0.f, 0.f, 0.f);
    float4 a1 = a0, a2 = a0, a3 = a0;

#pragma unroll 2
    for (int kc = 0; kc < 64; kc += 4) {
      float4 x0 = *(const float4*)&Xs[(r0 + 0) * 68 + kc];
      float4 x1 = *(const float4*)&Xs[(r0 + 1) * 68 + kc];
      float4 x2 = *(const float4*)&Xs[(r0 + 2) * 68 + kc];
      float4 x3 = *(const float4*)&Xs[(r0 + 3) * 68 + kc];
      const float* wp = &Ws[(size_t)kc * (64 * NCB) + cb * 64 + c0];
      float4 w0 = *(const float4*)(wp + 0 * (64 * NCB));
      float4 w1 = *(const float4*)(wp + 1 * (64 * NCB));
      float4 w2 = *(const float4*)(wp + 2 * (64 * NCB));
      float4 w3 = *(const float4*)(wp + 3 * (64 * NCB));
      a0.x = fmaf(x0.x, w0.x, a0.x); a0.y = fmaf(x0.x, w0.y, a0.y);
      a0.z = fmaf(x0.x, w0.z, a0.z); a0.w = fmaf(x0.x, w0.w, a0.w);
      a0.x = fmaf(x0.y, w1.x, a0.x); a0.y = fmaf(x0.y, w1.y, a0.y);
      a0.z = fmaf(x0.y, w1.z, a0.z); a0.w = fmaf(x0.y, w1.w, a0.w);
      a0.x = fmaf(x0.z, w2.x, a0.x); a0.y = fmaf(x0.z, w2.y, a0.y);
      a0.z = fmaf(x0.z, w2.z, a0.z); a0.w = fmaf(x0.z, w2.w, a0.w);
      a0.x = fmaf(x0.w, w3.x, a0.x); a0.y = fmaf(x0.w, w3.y, a0.y);
      a0.z = fmaf(x0.w, w3.z, a0.z); a0.w = fmaf(x0.w, w3.w, a0.w);
      a1.x = fmaf(x1.x, w0.x, a1.x); a1.y = fmaf(x1.x, w0.y, a1.y);
      a1.z = fmaf(x1.x, w0.z, a1.z); a1.w = fmaf(x1.x, w0.w, a1.w);
      a1.x = fmaf(x1.y, w1.x, a1.x); a1.y = fmaf(x1.y, w1.y, a1.y);
      a1.z = fmaf(x1.y, w1.z, a1.z); a1.w = fmaf(x1.y, w1.w, a1.w);
      a1.x = fmaf(x1.z, w2.x, a1.x); a1.y = fmaf(x1.z, w2.y, a1.y);
      a1.z = fmaf(x1.z, w2.z, a1.z); a1.w = fmaf(x1.z, w2.w, a1.w);
      a1.x = fmaf(x1.w, w3.x, a1.x); a1.y = fmaf(x1.w, w3.y, a1.y);
      a1.z = fmaf(x1.w, w3.z, a1.z); a1.w = fmaf(x1.w, w3.w, a1.w);
      a2.x = fmaf(x2.x, w0.x, a2.x); a2.y = fmaf(x2.x, w0.y, a2.y);
      a2.z = fmaf(x2.x, w0.z, a2.z); a2.w = fmaf(x2.x, w0.w, a2.w);
      a2.x = fmaf(x2.y, w1.x, a2.x); a2.y = fmaf(x2.y, w1.y, a2.y);
      a2.z = fmaf(x2.y, w1.z, a2.z); a2.w = fmaf(x2.y, w1.w, a2.w);
      a2.x = fmaf(x2.z, w2.x, a2.x); a2.y = fmaf(x2.z, w2.y, a2.y);
      a2.z = fmaf(x2.z, w2.z, a2.z); a2.w = fmaf(x2.z, w2.w, a2.w);
      a2.x = fmaf(x2.w, w3.x, a2.x); a2.y = fmaf(x2.w, w3.y, a2.y);
      a2.z = fmaf(x2.w, w3.z, a2.z); a2.w = fmaf(x2.w, w3.w, a2.w);
      a3.x = fmaf(x3.x, w0.x, a3.x); a3.y = fmaf(x3.x, w0.y, a3.y);
      a3.z = fmaf(x3.x, w0.z, a3.z); a3.w = fmaf(x3.x, w0.w, a3.w);
      a3.x = fmaf(x3.y, w1.x, a3.x); a3.y = fmaf(x3.y, w1.y, a3.y);
      a3.z = fmaf(x3.y, w1.z, a3.z); a3.w = fmaf(x3.y, w1.w, a3.w);
      a3.x = fmaf(x3.z, w2.x, a3.x); a3.y = fmaf(x3.z, w2.y, a3.y);
      a3.z = fmaf(x3.z, w2.z, a3.z); a3.w = fmaf(x3.z, w2.w, a3.w);
      a3.x = fmaf(x3.w, w3.x, a3.x); a3.y = fmaf(x3.w, w3.y, a3.y);
      a3.z = fmaf(x3.w, w3.z, a3.z); a3.w = fmaf(x3.w, w3.w, a3.w);
    }

    float4 bb = *(const float4*)&Bv[cb * 64 + c0];
#pragma unroll
    for (int ri = 0; ri < 4; ++ri) {
      int gr = gr0 + ri;
      if (gr >= n) break;
      float4 v = (ri == 0) ? a0 : (ri == 1) ? a1 : (ri == 2) ? a2 : a3;
      v.x += bb.x; v.y += bb.y; v.z += bb.z; v.w += bb.w;
      if (RELU) {
        v.x = fmaxf(v.x, 0.f); v.y = fmaxf(v.y, 0.f);
        v.z = fmaxf(v.z, 0.f); v.w = fmaxf(v.w, 0.f);
      }
      if (SCALE) {
        float s = dis[gr];
        v.x *= s; v.y *= s; v.z *= s; v.w *= s;
      }
      if (OUTH) {
        uint2 u;
        u.x = packh(v.x, v.y);
        u.y = packh(v.z, v.w);
        *(uint2*)(yH + (size_t)gr * 64 + c0) = u;
      } else {
        *(float4*)&yF[(size_t)gr * (64 * NCB) + cb * 64 + c0] = v;
      }
    }
  }
}

// ---------------- launch ----------------

extern "C" void kernel_launch(void* const* d_in, const int* in_sizes, int n_in,
                              void* d_out, int out_size, void* d_ws, size_t ws_size,
                              hipStream_t stream) {
  const float* x  = (const float*)d_in[0];
  const float* W1 = (const float*)d_in[1];
  const float* b1 = (const float*)d_in[2];
  const float* W2 = (const float*)d_in[3];
  const float* b2 = (const float*)d_in[4];
  const float* W3 = (const float*)d_in[5];
  const float* b3 = (const float*)d_in[6];
  const int*   ei = (const int*)d_in[7];

  const int n = in_sizes[0] / 64;   // 100000
  const int E = in_sizes[7] / 2;    // 1000000
  const int* src = ei;
  const int* dst = ei + E;

  const int NB    = (n + 255) >> 8;         // buckets (256 nodes each): 391
  const int nblkA = (E + EPB - 1) / EPB;    // binning blocks: 245

  // Workspace: dis[n] f32 | bufA[n*64] fp16 | bufB[n*64] fp16 | row_ptr[n+2] |
  //            csr_src[E] | pairs[E] int | hist[nblkA*NB] | tot[NB] | off[NB+1]
  float* dis = (float*)d_ws;
  unsigned short* bufA = (unsigned short*)(dis + n);
  unsigned short* bufB = bufA + (size_t)n * 64;
  int* row_ptr = (int*)(bufB + (size_t)n * 64);
  int* csr_src = row_ptr + (n + 2);
  int* pairs   = csr_src + E;
  int* hist       = pairs + E;
  int* bucket_tot = hist + (size_t)nblkA * NB;
  int* bucket_off = bucket_tot + NB;
  float* out = (float*)d_out;

  dim3 blk(256);
  int gL = (n + 63) / 64;         // fused layer: 64 nodes per block

  // --- bucketed CSR build (+ dis, + fused prescale into bufA) ---
  bin_hist<<<nblkA, blk, 0, stream>>>(dst, hist, E, NB);
  bucket_prefix<<<NB, blk, 0, stream>>>(hist, bucket_tot, nblkA, NB);
  bucket_scan<<<1, 512, 0, stream>>>(bucket_tot, bucket_off, NB, E);
  bin_scatter<<<nblkA, blk, 0, stream>>>(src, dst, hist, bucket_off, pairs, E, NB);
  bucket_fill<<<NB, blk, 0, stream>>>(pairs, bucket_off, row_ptr, csr_src, dis, x, bufA, n, NB);

  // --- Layer 1: fused gather+GEMM (relu, scale, fp16 out), bufA -> bufB ---
  gcn_layer<true, true, true, 1><<<gL, blk, 0, stream>>>(
      row_ptr, csr_src, bufA, dis, W1, b1, nullptr, bufB, n);

  // --- Layer 2: bufB -> bufA ---
  gcn_layer<true, true, true, 1><<<gL, blk, 0, stream>>>(
      row_ptr, csr_src, bufB, dis, W2, b2, nullptr, bufA, n);

  // --- Layer 3: bufA -> out (fp32, 128 cols) ---
  gcn_layer<false, false, false, 2><<<gL, blk, 0, stream>>>(
      row_ptr, csr_src, bufA, dis, W3, b3, out, nullptr, n);
}